// Round 12
// baseline (188.393 us; speedup 1.0000x reference)
//
#include <hip/hip_runtime.h>
#include <cstdint>
#include <cstddef>

// ---------------------------------------------------------------------------
// ChatGPTAttention: x[2,2048,1024] -> QKV proj -> causal MHA (16 heads, dk=64)
//                   -> O proj. bf16 MFMA pipeline, fp32 accumulate.
// Q pre-scaled by 1/8 in QKV-GEMM epilogue; V written transposed there (R14).
// LESSONS: (R5) LDS row stride mult of 8. (R6/R8) XOR swizzle for DMA LDS.
// (R11/R15) direct global frags fragment. (R18) split P buffers. (R19 FAILED)
// lag-1 PV spills. (R20 FAILED) direct-global V. (R21 NULL) per-CU balancing.
// (R22 WIN) 4-wave qxkv split 44.5->36.5. (R23 NEUTRAL) bt64 retile.
// (R24/R25 FAILED) 8-phase 256^2 QKV at K=1024. (R26 NEUTRAL) 8-wave attn.
// (R27 NEUTRAL) counted-vmcnt attn. (R28 NEUTRAL) counted-vmcnt gemm_bt:
// 40.96us, MfmaUtil 23.9 — drain theory dead for BOTH kernels.
// R29: gemm_bt stall signature = NO pipe >40% (MFMA 24%, LDS-read 37%, VALU
// 21%, HBM 19%) + drain removal null => LATENCY-BOUND, 12 waves/CU too few
// (same diagnosis as the R22 attn win). Fix: 128x64 tile, 2-buf staging
// (proven R14 discipline), LDS 24KB -> 6 blocks/CU = 24 waves/CU; per-wave
// iter chain 6 ds_read + 8 MFMA (was 8+16). Grid (48,32)=1536. Swizzle key
// unchanged (row len 32; (l15>>1)&3 cancels for 64-row B: wx*32>>1 mod 4=0).
// Falsifier: gemm_bt >= 40us => latency family dead too -> plateau account.
// ---------------------------------------------------------------------------

typedef __attribute__((ext_vector_type(8))) short bf16x8;   // MFMA A/B frag
typedef __attribute__((ext_vector_type(4))) float f32x4;    // MFMA C/D frag
typedef __attribute__((ext_vector_type(4))) unsigned int u32x4;   // 16B copy
typedef __attribute__((ext_vector_type(4))) unsigned short u16x4; // 8B store
typedef __attribute__((ext_vector_type(8))) unsigned short u16x8; // 16B store

__device__ __forceinline__ unsigned short f2b(float f) {  // RNE f32->bf16
  unsigned int u = __float_as_uint(f);
  u = u + 0x7FFFu + ((u >> 16) & 1u);
  return (unsigned short)(u >> 16);
}
__device__ __forceinline__ unsigned short f2b_trunc(float f) {  // truncate
  return (unsigned short)(__float_as_uint(f) >> 16);
}

// async global->LDS DMA, 16B per lane; LDS dest = wave base + lane*16
__device__ __forceinline__ void gl_lds16(const unsigned short* g, unsigned short* s) {
  __builtin_amdgcn_global_load_lds((const __attribute__((address_space(1))) void*)g,
                                   (__attribute__((address_space(3))) void*)s, 16, 0, 0);
}

// ---------------- fp32 -> bf16, all three inputs in one launch -------------
__global__ __launch_bounds__(256) void cvt_all(const float* __restrict__ x,
                                               const float* __restrict__ wq,
                                               const float* __restrict__ wo,
                                               unsigned short* __restrict__ xb,
                                               unsigned short* __restrict__ wqb,
                                               unsigned short* __restrict__ wob) {
  const int bid = blockIdx.x;
  const float* in;
  unsigned short* out;
  int base;
  if (bid < 4096)      { in = x;  out = xb;  base = bid; }
  else if (bid < 7168) { in = wq; out = wqb; base = bid - 4096; }
  else                 { in = wo; out = wob; base = bid - 7168; }
  const int idx = (base * 256 + threadIdx.x) * 4;
  f32x4 v = *(const f32x4*)(in + idx);
  u16x4 r;
  r[0] = f2b(v[0]); r[1] = f2b(v[1]); r[2] = f2b(v[2]); r[3] = f2b(v[3]);
  *(u16x4*)(out + idx) = r;
}

// ---------------- QKV GEMM: 128x64 tile, BK=32, 2-buf DMA ------------------
// C[M,N] = (A[M,K] * W[N,K]^T + bias) * colscale; V cols (>=2048) transposed
// into vtb. Grid (N/64=48, M/128=32) = 1536 blocks; LDS 24KB -> 6 blocks/CU
// = 24 waves/CU. Wave (wy,wx): 64 rows x 32 cols -> acc[4][2].
__global__ __launch_bounds__(256, 6) void gemm_bt(const unsigned short* __restrict__ A,
                                                  const unsigned short* __restrict__ W,
                                                  const float* __restrict__ bias,
                                                  unsigned short* __restrict__ Cb,
                                                  unsigned short* __restrict__ vtb,
                                                  int M, int N, int K, int qcols) {
  __shared__ unsigned short As[2][128 * 32];   // 8KB/buf
  __shared__ unsigned short Bs[2][64 * 32];    // 4KB/buf
  const int tid  = threadIdx.x;
  const int lane = tid & 63;
  const int w    = tid >> 6;
  const int wy   = w >> 1, wx = w & 1;
  const int l15  = lane & 15, quad = lane >> 4;
  const int xr2  = (l15 >> 1) & 3;
  const int m0 = blockIdx.y * 128, n0 = blockIdx.x * 64;

  // A: 512 chunks of 16B -> 2/thread. B: 256 chunks -> 1/thread.
  const unsigned short* gA[2];
  int offA[2];
#pragma unroll
  for (int p = 0; p < 2; ++p) {
    const int c = tid + p * 256;
    const int r = c >> 2;
    const int srcc = (c & 3) ^ ((r >> 1) & 3);
    gA[p] = A + (size_t)(m0 + r) * K + srcc * 8;
    offA[p] = c * 8;
  }
  const unsigned short* gB;
  int offB;
  {
    const int c = tid;
    const int r = c >> 2;
    const int srcc = (c & 3) ^ ((r >> 1) & 3);
    gB = W + (size_t)(n0 + r) * K + srcc * 8;
    offB = c * 8;
  }

  f32x4 acc[4][2];
#pragma unroll
  for (int i = 0; i < 4; ++i)
#pragma unroll
    for (int j = 0; j < 2; ++j) acc[i][j] = (f32x4){0.f, 0.f, 0.f, 0.f};

#pragma unroll
  for (int p = 0; p < 2; ++p) gl_lds16(gA[p], &As[0][offA[p]]);
  gl_lds16(gB, &Bs[0][offB]);

  const int NIT = K >> 5;
  for (int it = 0; it < NIT; ++it) {
    __syncthreads();
    const int cur = it & 1;
    if (it + 1 < NIT) {
      const int kt = (it + 1) << 5;
#pragma unroll
      for (int p = 0; p < 2; ++p) gl_lds16(gA[p] + kt, &As[cur ^ 1][offA[p]]);
      gl_lds16(gB + kt, &Bs[cur ^ 1][offB]);
    }
    const unsigned short* Ac = As[cur];
    const unsigned short* Bc = Bs[cur];
    bf16x8 af[4], bfr[2];
#pragma unroll
    for (int i = 0; i < 4; ++i)
      af[i] = *(const bf16x8*)&Ac[(wy * 64 + i * 16 + l15) * 32 + (quad ^ xr2) * 8];
#pragma unroll
    for (int j = 0; j < 2; ++j)
      bfr[j] = *(const bf16x8*)&Bc[(wx * 32 + j * 16 + l15) * 32 + (quad ^ xr2) * 8];
#pragma unroll
    for (int i = 0; i < 4; ++i)
#pragma unroll
      for (int j = 0; j < 2; ++j)
        acc[i][j] = __builtin_amdgcn_mfma_f32_16x16x32_bf16(af[i], bfr[j], acc[i][j], 0, 0, 0);
  }

  const bool vblock = (n0 >= 2048);  // block-uniform (64-col blocks)
#pragma unroll
  for (int i = 0; i < 4; ++i) {
    const int row = m0 + wy * 64 + i * 16 + quad * 4;
#pragma unroll
    for (int j = 0; j < 2; ++j) {
      const int col = n0 + wx * 32 + j * 16 + l15;
      const float bv = bias[col];
      if (!vblock) {
        const float sc = (col < qcols) ? 0.125f : 1.0f;
#pragma unroll
        for (int r = 0; r < 4; ++r)
          Cb[(size_t)(row + r) * N + col] = f2b((acc[i][j][r] + bv) * sc);
      } else {
        const int hd = col - 2048;
        const int bb = row >> 11, s = row & 2047;
        u16x4 ov;
#pragma unroll
        for (int r = 0; r < 4; ++r) ov[r] = f2b(acc[i][j][r] + bv);
        *(u16x4*)(vtb + ((size_t)(bb * 1024 + hd)) * 2048 + s) = ov;
      }
    }
  }
}

// ---------------- GEMM 128x64 tile, fp32 out (O-projection) ----------------
// R23 config. Grid (16,32)=512 blocks, LDS 48KB.
__global__ __launch_bounds__(256) void gemm_bt64(const unsigned short* __restrict__ A,
                                                 const unsigned short* __restrict__ W,
                                                 const float* __restrict__ bias,
                                                 float* __restrict__ Cf,
                                                 int M, int N, int K) {
  __shared__ unsigned short As[2][128 * 64];
  __shared__ unsigned short Bs[2][64 * 64];
  const int tid  = threadIdx.x;
  const int lane = tid & 63;
  const int w    = tid >> 6;
  const int wy   = w >> 1, wx = w & 1;
  const int l15  = lane & 15, quad = lane >> 4;
  const int xr   = l15 & 7;
  const int m0 = blockIdx.y * 128, n0 = blockIdx.x * 64;

  const unsigned short* gA[4];
  int offA[4];
#pragma unroll
  for (int p = 0; p < 4; ++p) {
    const int c = tid + p * 256;
    const int r = c >> 3;
    const int sc = ((c & 7) ^ (r & 7)) * 8;
    gA[p] = A + (size_t)(m0 + r) * K + sc;
    offA[p] = c * 8;
  }
  const unsigned short* gB[2];
  int offB[2];
#pragma unroll
  for (int p = 0; p < 2; ++p) {
    const int c = tid + p * 256;
    const int r = c >> 3;
    const int sc = ((c & 7) ^ (r & 7)) * 8;
    gB[p] = W + (size_t)(n0 + r) * K + sc;
    offB[p] = c * 8;
  }

  f32x4 acc[4][2];
#pragma unroll
  for (int i = 0; i < 4; ++i)
#pragma unroll
    for (int j = 0; j < 2; ++j) acc[i][j] = (f32x4){0.f, 0.f, 0.f, 0.f};

#pragma unroll
  for (int p = 0; p < 4; ++p) gl_lds16(gA[p], &As[0][offA[p]]);
#pragma unroll
  for (int p = 0; p < 2; ++p) gl_lds16(gB[p], &Bs[0][offB[p]]);

  const int NIT = K >> 6;
  for (int it = 0; it < NIT; ++it) {
    __syncthreads();
    const int cur = it & 1;
    if (it + 1 < NIT) {
      const int kt = (it + 1) << 6;
#pragma unroll
      for (int p = 0; p < 4; ++p) gl_lds16(gA[p] + kt, &As[cur ^ 1][offA[p]]);
#pragma unroll
      for (int p = 0; p < 2; ++p) gl_lds16(gB[p] + kt, &Bs[cur ^ 1][offB[p]]);
    }
    const unsigned short* Ac = As[cur];
    const unsigned short* Bc = Bs[cur];
#pragma unroll
    for (int kc = 0; kc < 2; ++kc) {
      bf16x8 af[4], bfr[2];
#pragma unroll
      for (int i = 0; i < 4; ++i)
        af[i] = *(const bf16x8*)&Ac[(wy * 64 + i * 16 + l15) * 64 + ((kc * 4 + quad) ^ xr) * 8];
#pragma unroll
      for (int j = 0; j < 2; ++j)
        bfr[j] = *(const bf16x8*)&Bc[(wx * 32 + j * 16 + l15) * 64 + ((kc * 4 + quad) ^ xr) * 8];
#pragma unroll
      for (int i = 0; i < 4; ++i)
#pragma unroll
        for (int j = 0; j < 2; ++j)
          acc[i][j] = __builtin_amdgcn_mfma_f32_16x16x32_bf16(af[i], bfr[j], acc[i][j], 0, 0, 0);
    }
  }

#pragma unroll
  for (int i = 0; i < 4; ++i) {
    const int row = m0 + wy * 64 + i * 16 + quad * 4;
#pragma unroll
    for (int j = 0; j < 2; ++j) {
      const int col = n0 + wx * 32 + j * 16 + l15;
      const float bv = bias[col];
#pragma unroll
      for (int r = 0; r < 4; ++r)
        Cf[(size_t)(row + r) * N + col] = acc[i][j][r] + bv;
    }
  }
}

// ---------------- flash attention v19: 8-wave q x kv split (R26) -----------
// Block = 8 waves (wq 0..3 x wk 0..1), 512 thr; grid (bh 32, y 32). Wave:
// 16 q x 32 kv. Plain dbuf __syncthreads staging. Combine via dead Ks/Vs.
__global__ __launch_bounds__(512, 6) void attn_fwd(const unsigned short* __restrict__ qkv,
                                                   const unsigned short* __restrict__ vt,
                                                   unsigned short* __restrict__ o) {
  __shared__ unsigned short Ks[2][64 * 64];
  __shared__ unsigned short Vs[2][64 * 64];
  __shared__ unsigned short pbuf[8][16 * 40];  // [wave][16 q x (32+8) kv]
  const int tid  = threadIdx.x;
  const int lane = tid & 63;
  const int w    = tid >> 6;          // 8 waves
  const int wq   = w & 3;             // q-quarter (16 q)
  const int wk   = w >> 2;            // kv-half (32 kv)
  const int l15  = lane & 15, quad = lane >> 4;
  const int xr   = l15 & 7;
  const int bh = blockIdx.x, b = bh >> 4, h = bh & 15;
  const int y  = (int)blockIdx.y;
  const int qt = (y < 16) ? y : 47 - y;  // per-CU balanced (R21)
  const int q0 = qt * 64;
  const int T = qt + 1;
  const int qs = q0 + wq * 16;        // this wave's q base (16 rows)

  // DMA staging: 512 chunks per 64x64 tile / 512 threads = 1/thread/array.
  const int r  = tid >> 3;
  const int sc = ((tid & 7) ^ (r & 7)) * 8;
  const unsigned short* gKd = qkv + (size_t)(b * 2048 + r) * 3072 + 1024 + h * 64 + sc;
  const unsigned short* gVd = vt + (size_t)(bh * 64 + r) * 2048 + sc;
  const int doff = tid * 8;

  const unsigned short* qr = qkv + (size_t)(b * 2048 + qs + l15) * 3072 + h * 64;
  const bf16x8 bq[2] = { *(const bf16x8*)(qr + quad * 8),
                         *(const bf16x8*)(qr + 32 + quad * 8) };

  bf16x8 vones;
#pragma unroll
  for (int k = 0; k < 8; ++k) vones[k] = (short)0x3F80;  // bf16 1.0

  f32x4 acc[4];      // [d-tile], PARTIAL over this wave's kv-half
#pragma unroll
  for (int j = 0; j < 4; ++j) acc[j] = (f32x4){0.f, 0.f, 0.f, 0.f};
  f32x4 accL = (f32x4){0.f, 0.f, 0.f, 0.f};

  unsigned short* P = pbuf[w];

  // prologue: DMA tile 0 -> buf 0
  gl_lds16(gKd, &Ks[0][doff]);
  gl_lds16(gVd, &Vs[0][doff]);

  for (int t = 0; t < T; ++t) {
    __syncthreads();  // drains DMA for buf(t&1)
    const int cur = t & 1;
    if (t + 1 < T) {
      const size_t ko = (size_t)(t + 1) * 64 * 3072;
      const int vo = (t + 1) * 64;
      gl_lds16(gKd + ko, &Ks[cur ^ 1][doff]);
      gl_lds16(gVd + vo, &Vs[cur ^ 1][doff]);
    }
    const unsigned short* Kc = Ks[cur];
    const unsigned short* Vc = Vs[cur];
    const int kv0 = t * 64 + wk * 32;   // this wave's kv base

    // ---- S^T[kv][q] = K Q^T, this wave's 32 kv x 16 q ----
    f32x4 st[2];
#pragma unroll
    for (int n = 0; n < 2; ++n) {
      const int row = wk * 32 + n * 16 + l15;
      const bf16x8 kA0 = *(const bf16x8*)&Kc[row * 64 + ((quad) ^ xr) * 8];
      const bf16x8 kA1 = *(const bf16x8*)&Kc[row * 64 + ((4 + quad) ^ xr) * 8];
      f32x4 z = (f32x4){0.f, 0.f, 0.f, 0.f};
      z = __builtin_amdgcn_mfma_f32_16x16x32_bf16(kA0, bq[0], z, 0, 0, 0);
      z = __builtin_amdgcn_mfma_f32_16x16x32_bf16(kA1, bq[1], z, 0, 0, 0);
      st[n] = z;
    }
    // ---- V^T A-frags for this kv-half ----
    bf16x8 av[4];
#pragma unroll
    for (int j = 0; j < 4; ++j) {
      const int row = j * 16 + l15;
      av[j] = *(const bf16x8*)&Vc[row * 64 + ((wk * 4 + quad) ^ xr) * 8];
    }
    // ---- mask/exp + P write ----
    if (kv0 + 31 > qs) {
      const int qrow = qs + l15;
#pragma unroll
      for (int n = 0; n < 2; ++n)
#pragma unroll
        for (int rr = 0; rr < 4; ++rr)
          if (kv0 + n * 16 + quad * 4 + rr > qrow) st[n][rr] = -1e30f;
    }
#pragma unroll
    for (int n = 0; n < 2; ++n) {
#pragma unroll
      for (int rr = 0; rr < 4; ++rr) st[n][rr] = __expf(st[n][rr]);
      u16x4 pw;
      pw[0] = f2b_trunc(st[n][0]); pw[1] = f2b_trunc(st[n][1]);
      pw[2] = f2b_trunc(st[n][2]); pw[3] = f2b_trunc(st[n][3]);
      *(u16x4*)&P[l15 * 40 + n * 16 + quad * 4] = pw;
    }
    // ---- Pr + PV (K=32 contraction) ----
    {
      const bf16x8 bp = *(const bf16x8*)&P[l15 * 40 + quad * 8];
      accL = __builtin_amdgcn_mfma_f32_16x16x32_bf16(vones, bp, accL, 0, 0, 0);
#pragma unroll
      for (int j = 0; j < 4; ++j)
        acc[j] = __builtin_amdgcn_mfma_f32_16x16x32_bf16(av[j], bp, acc[j], 0, 0, 0);
    }
  }

  // ---- cross-wave kv-half combine (once per block; K/V buffers dead) ----
  __syncthreads();
  float* cmbA = (float*)&Ks[0][0];   // 16 frags x 1KB = 16KB = Ks
  float* cmbL = (float*)&Vs[0][0];   // 4 x 64 floats = 1KB
  if (wk == 1) {
    cmbL[wq * 64 + lane] = accL[0];
#pragma unroll
    for (int j = 0; j < 4; ++j)
      *(f32x4*)&cmbA[((wq * 4 + j) << 8) + lane * 4] = acc[j];
  }
  __syncthreads();
  if (wk == 0) {
    const float lsum = accL[0] + cmbL[wq * 64 + lane];
    const float inv = 1.0f / lsum;
    const int qrow = qs + l15;
    unsigned short* orow = o + (size_t)(b * 2048 + qrow) * 1024 + h * 64;
#pragma unroll
    for (int j = 0; j < 4; ++j) {
      const f32x4 oth = *(const f32x4*)&cmbA[((wq * 4 + j) << 8) + lane * 4];
      u16x4 ov;
      ov[0] = f2b((acc[j][0] + oth[0]) * inv);
      ov[1] = f2b((acc[j][1] + oth[1]) * inv);
      ov[2] = f2b((acc[j][2] + oth[2]) * inv);
      ov[3] = f2b((acc[j][3] + oth[3]) * inv);
      *(u16x4*)(orow + j * 16 + quad * 4) = ov;
    }
  }
}

// ---------------------------------------------------------------------------
extern "C" void kernel_launch(void* const* d_in, const int* in_sizes, int n_in,
                              void* d_out, int out_size, void* d_ws, size_t ws_size,
                              hipStream_t stream) {
  const float* x       = (const float*)d_in[0];
  // d_in[1] = mask: causal tril by construction; implemented analytically.
  const float* w_qkv_w = (const float*)d_in[2];
  const float* w_qkv_b = (const float*)d_in[3];
  const float* w_o_w   = (const float*)d_in[4];
  const float* w_o_b   = (const float*)d_in[5];
  float* out = (float*)d_out;

  unsigned short* ws    = (unsigned short*)d_ws;
  unsigned short* xb    = ws;                                  // 4096*1024
  unsigned short* wqb   = xb   + (size_t)4096 * 1024;          // 3072*1024
  unsigned short* wob   = wqb  + (size_t)3072 * 1024;          // 1024*1024
  unsigned short* qkvb  = wob  + (size_t)1024 * 1024;          // 4096*3072
  unsigned short* vtb   = qkvb + (size_t)4096 * 3072;          // 2048*2048
  unsigned short* attnb = vtb  + (size_t)2048 * 2048;          // 4096*1024

  cvt_all<<<8192, 256, 0, stream>>>(x, w_qkv_w, w_o_w, xb, wqb, wob);
  gemm_bt<<<dim3(48, 32), 256, 0, stream>>>(xb, wqb, w_qkv_b, qkvb, vtb, 4096, 3072, 1024, 1024);
  attn_fwd<<<dim3(32, 32), 512, 0, stream>>>(qkvb, vtb, attnb);
  gemm_bt64<<<dim3(16, 32), 256, 0, stream>>>(attnb, wob, w_o_b, out, 4096, 1024, 1024);
}

// Round 13
// 180.316 us; speedup vs baseline: 1.0448x; 1.0448x over previous
//
#include <hip/hip_runtime.h>
#include <cstdint>
#include <cstddef>

// ---------------------------------------------------------------------------
// ChatGPTAttention: x[2,2048,1024] -> QKV proj -> causal MHA (16 heads, dk=64)
//                   -> O proj. bf16 MFMA pipeline, fp32 accumulate.
// Q pre-scaled by 1/8 in QKV-GEMM epilogue; V written transposed there (R14).
// LESSONS: (R5) LDS row stride mult of 8 OR XOR slot swizzle. (R6/R8) XOR
// swizzle for DMA LDS. (R18) split P buffers. (R19/R20 FAILED) lag-1 PV /
// direct-global V. (R21 NULL) balancing. (R22 WIN) 4-wave qxkv 44.5->36.5.
// (R24/R25 FAILED) 8-phase 256^2 at K=1024. (R26/R27/R28 NULL) 8-wave split /
// counted-vmcnt attn / counted-vmcnt gemm. (R29 FAILED) 128x64 gemm_bt:
// 52.8us despite 47% occupancy — smaller tiles = more traffic, still
// latency-bound. gemm_bt REVERTED to R14 128^2 (40.6us proven).
// MODEL UPDATE (R30): no pipe >40% in either kernel; attn v18 (38KB LDS/tile,
// 12 waves) == v19 (74KB, 24 waves) in time -> not LDS/TLP/chain-bound.
// attn cost scales with TILE COUNT (66 tiles/CU x ~1300cyc = 36.1us ~= meas).
// R30 v21: KVBLK 64->128 on the v18 4-wave structure — halves barriers and
// per-tile fixed cost, doubles per-barrier pipeline depth. P buffer drops
// +8 pad for XOR slot swizzle (stride 64; write slot^xr, read quad^xr, same
// involution) -> LDS exactly 80KB = 2 blocks/CU. Per-CU load still balanced
// (residue-class sum of T128 constant). Falsifier: attn >= 38us => TLP loss
// dominates -> revert to 177.4 config next round.
// ---------------------------------------------------------------------------

typedef __attribute__((ext_vector_type(8))) short bf16x8;   // MFMA A/B frag
typedef __attribute__((ext_vector_type(4))) float f32x4;    // MFMA C/D frag
typedef __attribute__((ext_vector_type(4))) unsigned int u32x4;   // 16B copy
typedef __attribute__((ext_vector_type(4))) unsigned short u16x4; // 8B store
typedef __attribute__((ext_vector_type(8))) unsigned short u16x8; // 16B store

__device__ __forceinline__ unsigned short f2b(float f) {  // RNE f32->bf16
  unsigned int u = __float_as_uint(f);
  u = u + 0x7FFFu + ((u >> 16) & 1u);
  return (unsigned short)(u >> 16);
}
__device__ __forceinline__ unsigned short f2b_trunc(float f) {  // truncate
  return (unsigned short)(__float_as_uint(f) >> 16);
}

// async global->LDS DMA, 16B per lane; LDS dest = wave base + lane*16
__device__ __forceinline__ void gl_lds16(const unsigned short* g, unsigned short* s) {
  __builtin_amdgcn_global_load_lds((const __attribute__((address_space(1))) void*)g,
                                   (__attribute__((address_space(3))) void*)s, 16, 0, 0);
}

// ---------------- fp32 -> bf16, all three inputs in one launch -------------
__global__ __launch_bounds__(256) void cvt_all(const float* __restrict__ x,
                                               const float* __restrict__ wq,
                                               const float* __restrict__ wo,
                                               unsigned short* __restrict__ xb,
                                               unsigned short* __restrict__ wqb,
                                               unsigned short* __restrict__ wob) {
  const int bid = blockIdx.x;
  const float* in;
  unsigned short* out;
  int base;
  if (bid < 4096)      { in = x;  out = xb;  base = bid; }
  else if (bid < 7168) { in = wq; out = wqb; base = bid - 4096; }
  else                 { in = wo; out = wob; base = bid - 7168; }
  const int idx = (base * 256 + threadIdx.x) * 4;
  f32x4 v = *(const f32x4*)(in + idx);
  u16x4 r;
  r[0] = f2b(v[0]); r[1] = f2b(v[1]); r[2] = f2b(v[2]); r[3] = f2b(v[3]);
  *(u16x4*)(out + idx) = r;
}

// ---------------- GEMM: C[M,N] = (A[M,K] * W[N,K]^T + bias) * colscale -----
// 128x128 tile, BK=32, dbuf DMA (32KB LDS). V-column blocks (n0>=2048) write
// transposed into vt as packed u16x4. PROVEN R14 structure (40.6us measured).
__global__ __launch_bounds__(256) void gemm_bt(const unsigned short* __restrict__ A,
                                               const unsigned short* __restrict__ W,
                                               const float* __restrict__ bias,
                                               unsigned short* __restrict__ Cb,
                                               unsigned short* __restrict__ vtb,
                                               int M, int N, int K, int qcols) {
  __shared__ unsigned short As[2][128 * 32];
  __shared__ unsigned short Bs[2][128 * 32];
  const int tid  = threadIdx.x;
  const int lane = tid & 63;
  const int w    = tid >> 6;
  const int wy   = w >> 1, wx = w & 1;
  const int l15  = lane & 15, quad = lane >> 4;
  const int xr2  = (l15 >> 1) & 3;
  const int m0 = blockIdx.y * 128, n0 = blockIdx.x * 128;

  const unsigned short* gA[2];
  const unsigned short* gB[2];
  int off[2];
#pragma unroll
  for (int p = 0; p < 2; ++p) {
    const int c = tid + p * 256;
    const int r = c >> 2;
    const int srcc = (c & 3) ^ ((r >> 1) & 3);
    gA[p] = A + (size_t)(m0 + r) * K + srcc * 8;
    gB[p] = W + (size_t)(n0 + r) * K + srcc * 8;
    off[p] = c * 8;
  }

  f32x4 acc[4][4];
#pragma unroll
  for (int i = 0; i < 4; ++i)
#pragma unroll
    for (int j = 0; j < 4; ++j) acc[i][j] = (f32x4){0.f, 0.f, 0.f, 0.f};

#pragma unroll
  for (int p = 0; p < 2; ++p) {
    gl_lds16(gA[p], &As[0][off[p]]);
    gl_lds16(gB[p], &Bs[0][off[p]]);
  }

  const int NIT = K >> 5;
  for (int it = 0; it < NIT; ++it) {
    __syncthreads();
    const int cur = it & 1;
    if (it + 1 < NIT) {
      const int kt = (it + 1) << 5;
#pragma unroll
      for (int p = 0; p < 2; ++p) {
        gl_lds16(gA[p] + kt, &As[cur ^ 1][off[p]]);
        gl_lds16(gB[p] + kt, &Bs[cur ^ 1][off[p]]);
      }
    }
    const unsigned short* Ac = As[cur];
    const unsigned short* Bc = Bs[cur];
    bf16x8 af[4], bfr[4];
#pragma unroll
    for (int i = 0; i < 4; ++i)
      af[i] = *(const bf16x8*)&Ac[(wy * 64 + i * 16 + l15) * 32 + (quad ^ xr2) * 8];
#pragma unroll
    for (int j = 0; j < 4; ++j)
      bfr[j] = *(const bf16x8*)&Bc[(wx * 64 + j * 16 + l15) * 32 + (quad ^ xr2) * 8];
#pragma unroll
    for (int i = 0; i < 4; ++i)
#pragma unroll
      for (int j = 0; j < 4; ++j)
        acc[i][j] = __builtin_amdgcn_mfma_f32_16x16x32_bf16(af[i], bfr[j], acc[i][j], 0, 0, 0);
  }

  const bool vblock = (n0 >= 2048);  // block-uniform
#pragma unroll
  for (int i = 0; i < 4; ++i) {
    const int row = m0 + wy * 64 + i * 16 + quad * 4;
#pragma unroll
    for (int j = 0; j < 4; ++j) {
      const int col = n0 + wx * 64 + j * 16 + l15;
      const float bv = bias[col];
      if (!vblock) {
        const float sc = (col < qcols) ? 0.125f : 1.0f;
#pragma unroll
        for (int r = 0; r < 4; ++r)
          Cb[(size_t)(row + r) * N + col] = f2b((acc[i][j][r] + bv) * sc);
      } else {
        const int hd = col - 2048;
        const int bb = row >> 11, s = row & 2047;
        u16x4 ov;
#pragma unroll
        for (int r = 0; r < 4; ++r) ov[r] = f2b(acc[i][j][r] + bv);
        *(u16x4*)(vtb + ((size_t)(bb * 1024 + hd)) * 2048 + s) = ov;
      }
    }
  }
}

// ---------------- GEMM 128x64 tile, fp32 out (O-projection) ----------------
// R23 config. Grid (16,32)=512 blocks, LDS 48KB.
__global__ __launch_bounds__(256) void gemm_bt64(const unsigned short* __restrict__ A,
                                                 const unsigned short* __restrict__ W,
                                                 const float* __restrict__ bias,
                                                 float* __restrict__ Cf,
                                                 int M, int N, int K) {
  __shared__ unsigned short As[2][128 * 64];
  __shared__ unsigned short Bs[2][64 * 64];
  const int tid  = threadIdx.x;
  const int lane = tid & 63;
  const int w    = tid >> 6;
  const int wy   = w >> 1, wx = w & 1;
  const int l15  = lane & 15, quad = lane >> 4;
  const int xr   = l15 & 7;
  const int m0 = blockIdx.y * 128, n0 = blockIdx.x * 64;

  const unsigned short* gA[4];
  int offA[4];
#pragma unroll
  for (int p = 0; p < 4; ++p) {
    const int c = tid + p * 256;
    const int r = c >> 3;
    const int sc = ((c & 7) ^ (r & 7)) * 8;
    gA[p] = A + (size_t)(m0 + r) * K + sc;
    offA[p] = c * 8;
  }
  const unsigned short* gB[2];
  int offB[2];
#pragma unroll
  for (int p = 0; p < 2; ++p) {
    const int c = tid + p * 256;
    const int r = c >> 3;
    const int sc = ((c & 7) ^ (r & 7)) * 8;
    gB[p] = W + (size_t)(n0 + r) * K + sc;
    offB[p] = c * 8;
  }

  f32x4 acc[4][2];
#pragma unroll
  for (int i = 0; i < 4; ++i)
#pragma unroll
    for (int j = 0; j < 2; ++j) acc[i][j] = (f32x4){0.f, 0.f, 0.f, 0.f};

#pragma unroll
  for (int p = 0; p < 4; ++p) gl_lds16(gA[p], &As[0][offA[p]]);
#pragma unroll
  for (int p = 0; p < 2; ++p) gl_lds16(gB[p], &Bs[0][offB[p]]);

  const int NIT = K >> 6;
  for (int it = 0; it < NIT; ++it) {
    __syncthreads();
    const int cur = it & 1;
    if (it + 1 < NIT) {
      const int kt = (it + 1) << 6;
#pragma unroll
      for (int p = 0; p < 4; ++p) gl_lds16(gA[p] + kt, &As[cur ^ 1][offA[p]]);
#pragma unroll
      for (int p = 0; p < 2; ++p) gl_lds16(gB[p] + kt, &Bs[cur ^ 1][offB[p]]);
    }
    const unsigned short* Ac = As[cur];
    const unsigned short* Bc = Bs[cur];
#pragma unroll
    for (int kc = 0; kc < 2; ++kc) {
      bf16x8 af[4], bfr[2];
#pragma unroll
      for (int i = 0; i < 4; ++i)
        af[i] = *(const bf16x8*)&Ac[(wy * 64 + i * 16 + l15) * 64 + ((kc * 4 + quad) ^ xr) * 8];
#pragma unroll
      for (int j = 0; j < 2; ++j)
        bfr[j] = *(const bf16x8*)&Bc[(wx * 32 + j * 16 + l15) * 64 + ((kc * 4 + quad) ^ xr) * 8];
#pragma unroll
      for (int i = 0; i < 4; ++i)
#pragma unroll
        for (int j = 0; j < 2; ++j)
          acc[i][j] = __builtin_amdgcn_mfma_f32_16x16x32_bf16(af[i], bfr[j], acc[i][j], 0, 0, 0);
    }
  }

#pragma unroll
  for (int i = 0; i < 4; ++i) {
    const int row = m0 + wy * 64 + i * 16 + quad * 4;
#pragma unroll
    for (int j = 0; j < 2; ++j) {
      const int col = n0 + wx * 32 + j * 16 + l15;
      const float bv = bias[col];
#pragma unroll
      for (int r = 0; r < 4; ++r)
        Cf[(size_t)(row + r) * N + col] = acc[i][j][r] + bv;
    }
  }
}

// ---------------- flash attention v21: v18 4-wave + KVBLK=128 --------------
// Block = 4 waves (wq 0..1 x wk 0..1), 256 thr; grid (bh 32, y 32). Wave:
// 32 q (2 subtiles) x 64 kv (half of 128-kv tile). T = qt/2+1 tiles ->
// barriers halved vs KVBLK=64. K staged [128kv][64d], V staged [64d][128kv],
// both XOR-swizzled. P per wave per subtile 16x64 XOR-slot-swizzled (no pad).
// LDS = 2*16K(K) + 2*16K(V) + 16K(P) = 80KB -> 2 blocks/CU. Combine via dead
// Ks/Vs. Load balanced: residue-class sum of T128 is constant (=35).
__global__ __launch_bounds__(256, 2) void attn_fwd(const unsigned short* __restrict__ qkv,
                                                   const unsigned short* __restrict__ vt,
                                                   unsigned short* __restrict__ o) {
  __shared__ unsigned short Ks[2][128 * 64];   // [kv 128][d 64]
  __shared__ unsigned short Vs[2][64 * 128];   // [d 64][kv 128]
  __shared__ unsigned short pbuf[4][2][16 * 64];  // [wave][subtile][16q x 64kv]
  const int tid  = threadIdx.x;
  const int lane = tid & 63;
  const int w    = tid >> 6;          // 4 waves
  const int wq   = w & 1;             // q-half (32 q)
  const int wk   = w >> 1;            // kv-half (64 of 128)
  const int l15  = lane & 15, quad = lane >> 4;
  const int xr   = l15 & 7;
  const int bh = blockIdx.x, b = bh >> 4, h = bh & 15;
  const int y  = (int)blockIdx.y;
  const int qt = (y < 16) ? y : 47 - y;  // per-CU balanced (R21)
  const int q0 = qt * 64;
  const int T = (qt >> 1) + 1;        // 128-kv tiles; T*128 <= 2048 always
  const int qs0 = q0 + wq * 32;       // subtile 0 base
  const int qs1 = qs0 + 16;           // subtile 1 base

  // K staging: 128 rows x 8 chunks = 1024 chunks -> 4/thread.
  const unsigned short* gKd[4];
  int dKoff[4];
#pragma unroll
  for (int p = 0; p < 4; ++p) {
    const int c = tid + p * 256;
    const int r = c >> 3;                       // kv row 0..127
    const int sc = ((c & 7) ^ (r & 7)) * 8;
    gKd[p] = qkv + (size_t)(b * 2048 + r) * 3072 + 1024 + h * 64 + sc;
    dKoff[p] = c * 8;
  }
  // V staging: 64 rows x 16 chunks = 1024 chunks -> 4/thread.
  const unsigned short* gVd[4];
  int dVoff[4];
#pragma unroll
  for (int p = 0; p < 4; ++p) {
    const int c = tid + p * 256;
    const int rv = c >> 4;                      // d row 0..63
    const int sv = ((c & 15) ^ (rv & 7)) * 8;   // 4-bit slot ^ 3-bit key
    gVd[p] = vt + (size_t)(bh * 64 + rv) * 2048 + sv;
    dVoff[p] = c * 8;
  }

  const unsigned short* qr0 = qkv + (size_t)(b * 2048 + qs0 + l15) * 3072 + h * 64;
  const unsigned short* qr1 = qkv + (size_t)(b * 2048 + qs1 + l15) * 3072 + h * 64;
  const bf16x8 bq[2][2] = {
    { *(const bf16x8*)(qr0 + quad * 8), *(const bf16x8*)(qr0 + 32 + quad * 8) },
    { *(const bf16x8*)(qr1 + quad * 8), *(const bf16x8*)(qr1 + 32 + quad * 8) } };

  bf16x8 vones;
#pragma unroll
  for (int k = 0; k < 8; ++k) vones[k] = (short)0x3F80;  // bf16 1.0

  f32x4 acc[2][4];   // [subtile][d-tile], PARTIAL over this wave's kv-half
#pragma unroll
  for (int i = 0; i < 2; ++i)
#pragma unroll
    for (int j = 0; j < 4; ++j) acc[i][j] = (f32x4){0.f, 0.f, 0.f, 0.f};
  f32x4 accL[2] = {(f32x4){0.f, 0.f, 0.f, 0.f}, (f32x4){0.f, 0.f, 0.f, 0.f}};

  unsigned short* P0 = pbuf[w][0];
  unsigned short* P1 = pbuf[w][1];

  // prologue: DMA tile 0 -> buf 0
#pragma unroll
  for (int p = 0; p < 4; ++p) gl_lds16(gKd[p], &Ks[0][dKoff[p]]);
#pragma unroll
  for (int p = 0; p < 4; ++p) gl_lds16(gVd[p], &Vs[0][dVoff[p]]);

  for (int t = 0; t < T; ++t) {
    __syncthreads();  // drains DMA for buf(t&1)
    const int cur = t & 1;
    if (t + 1 < T) {
      const size_t ko = (size_t)(t + 1) * 128 * 3072;
      const int vo = (t + 1) * 128;
#pragma unroll
      for (int p = 0; p < 4; ++p) gl_lds16(gKd[p] + ko, &Ks[cur ^ 1][dKoff[p]]);
#pragma unroll
      for (int p = 0; p < 4; ++p) gl_lds16(gVd[p] + vo, &Vs[cur ^ 1][dVoff[p]]);
    }
    const unsigned short* Kc = Ks[cur];
    const unsigned short* Vc = Vs[cur];
    const int kv0 = t * 128 + wk * 64;   // this wave's kv base (64 wide)

    // ---- S^T[kv][q] = K Q^T: 4 kv-subtiles x 2 q-subtiles ----
    f32x4 st[2][4];
#pragma unroll
    for (int n = 0; n < 4; ++n) {
      const int row = wk * 64 + n * 16 + l15;    // row&7 == xr (64,16 mult of 8)
      const bf16x8 kA0 = *(const bf16x8*)&Kc[row * 64 + ((quad) ^ xr) * 8];
      const bf16x8 kA1 = *(const bf16x8*)&Kc[row * 64 + ((4 + quad) ^ xr) * 8];
      f32x4 z0 = (f32x4){0.f, 0.f, 0.f, 0.f};
      z0 = __builtin_amdgcn_mfma_f32_16x16x32_bf16(kA0, bq[0][0], z0, 0, 0, 0);
      z0 = __builtin_amdgcn_mfma_f32_16x16x32_bf16(kA1, bq[0][1], z0, 0, 0, 0);
      st[0][n] = z0;
      f32x4 z1 = (f32x4){0.f, 0.f, 0.f, 0.f};
      z1 = __builtin_amdgcn_mfma_f32_16x16x32_bf16(kA0, bq[1][0], z1, 0, 0, 0);
      z1 = __builtin_amdgcn_mfma_f32_16x16x32_bf16(kA1, bq[1][1], z1, 0, 0, 0);
      st[1][n] = z1;
    }
    // ---- V^T A-frags for this wave's kv-half (cols wk*64..wk*64+63) ----
    bf16x8 av[4][2];
#pragma unroll
    for (int j = 0; j < 4; ++j) {
      const int row = j * 16 + l15;              // d row; key row&7 == xr
      av[j][0] = *(const bf16x8*)&Vc[row * 128 + ((wk * 8 + quad) ^ xr) * 8];
      av[j][1] = *(const bf16x8*)&Vc[row * 128 + ((wk * 8 + 4 + quad) ^ xr) * 8];
    }
    // ---- mask/exp + P writes (XOR slot swizzle, stride 64) ----
#pragma unroll
    for (int s = 0; s < 2; ++s) {
      unsigned short* P = s ? P1 : P0;
      const int qbase = s ? qs1 : qs0;
      if (kv0 + 63 > qbase) {
        const int qrow = qbase + l15;
#pragma unroll
        for (int n = 0; n < 4; ++n)
#pragma unroll
          for (int rr = 0; rr < 4; ++rr)
            if (kv0 + n * 16 + quad * 4 + rr > qrow) st[s][n][rr] = -1e30f;
      }
#pragma unroll
      for (int n = 0; n < 4; ++n) {
#pragma unroll
        for (int rr = 0; rr < 4; ++rr) st[s][n][rr] = __expf(st[s][n][rr]);
        u16x4 pw;
        pw[0] = f2b_trunc(st[s][n][0]); pw[1] = f2b_trunc(st[s][n][1]);
        pw[2] = f2b_trunc(st[s][n][2]); pw[3] = f2b_trunc(st[s][n][3]);
        const int slot = n * 2 + (quad >> 1);    // (n*16+quad*4)>>3
        *(u16x4*)&P[l15 * 64 + ((slot ^ xr) * 8) + (quad & 1) * 4] = pw;
      }
    }
    // ---- Pr + PV: contraction over this wave's 64 kv = 2 MFMAs/frag ----
#pragma unroll
    for (int s = 0; s < 2; ++s) {
      const unsigned short* P = s ? P1 : P0;
      const bf16x8 bp0 = *(const bf16x8*)&P[l15 * 64 + ((quad ^ xr) * 8)];
      const bf16x8 bp1 = *(const bf16x8*)&P[l15 * 64 + (((4 + quad) ^ xr) * 8)];
      accL[s] = __builtin_amdgcn_mfma_f32_16x16x32_bf16(vones, bp0, accL[s], 0, 0, 0);
      accL[s] = __builtin_amdgcn_mfma_f32_16x16x32_bf16(vones, bp1, accL[s], 0, 0, 0);
#pragma unroll
      for (int j = 0; j < 4; ++j) {
        acc[s][j] = __builtin_amdgcn_mfma_f32_16x16x32_bf16(av[j][0], bp0, acc[s][j], 0, 0, 0);
        acc[s][j] = __builtin_amdgcn_mfma_f32_16x16x32_bf16(av[j][1], bp1, acc[s][j], 0, 0, 0);
      }
    }
  }

  // ---- cross-wave kv-half combine (once per block; K/V buffers dead) ----
  __syncthreads();
  float* cmbA = (float*)&Ks[0][0];   // 16 frags x 256 floats = 16KB = Ks[0]
  float* cmbL = (float*)&Vs[0][0];   // 4 x 64 floats = 1KB
  if (wk == 1) {
#pragma unroll
    for (int s = 0; s < 2; ++s) {
      cmbL[(wq * 2 + s) * 64 + lane] = accL[s][0];
#pragma unroll
      for (int j = 0; j < 4; ++j)
        *(f32x4*)&cmbA[(((wq * 2 + s) * 4 + j) << 8) + lane * 4] = acc[s][j];
    }
  }
  __syncthreads();
  if (wk == 0) {
#pragma unroll
    for (int s = 0; s < 2; ++s) {
      const float lsum = accL[s][0] + cmbL[(wq * 2 + s) * 64 + lane];
      const float inv = 1.0f / lsum;
      const int qrow = (s ? qs1 : qs0) + l15;
      unsigned short* orow = o + (size_t)(b * 2048 + qrow) * 1024 + h * 64;
#pragma unroll
      for (int j = 0; j < 4; ++j) {
        const f32x4 oth = *(const f32x4*)&cmbA[(((wq * 2 + s) * 4 + j) << 8) + lane * 4];
        u16x4 ov;
        ov[0] = f2b((acc[s][j][0] + oth[0]) * inv);
        ov[1] = f2b((acc[s][j][1] + oth[1]) * inv);
        ov[2] = f2b((acc[s][j][2] + oth[2]) * inv);
        ov[3] = f2b((acc[s][j][3] + oth[3]) * inv);
        *(u16x4*)(orow + j * 16 + quad * 4) = ov;
      }
    }
  }
}

// ---------------------------------------------------------------------------
extern "C" void kernel_launch(void* const* d_in, const int* in_sizes, int n_in,
                              void* d_out, int out_size, void* d_ws, size_t ws_size,
                              hipStream_t stream) {
  const float* x       = (const float*)d_in[0];
  // d_in[1] = mask: causal tril by construction; implemented analytically.
  const float* w_qkv_w = (const float*)d_in[2];
  const float* w_qkv_b = (const float*)d_in[3];
  const float* w_o_w   = (const float*)d_in[4];
  const float* w_o_b   = (const float*)d_in[5];
  float* out = (float*)d_out;

  unsigned short* ws    = (unsigned short*)d_ws;
  unsigned short* xb    = ws;                                  // 4096*1024
  unsigned short* wqb   = xb   + (size_t)4096 * 1024;          // 3072*1024
  unsigned short* wob   = wqb  + (size_t)3072 * 1024;          // 1024*1024
  unsigned short* qkvb  = wob  + (size_t)1024 * 1024;          // 4096*3072
  unsigned short* vtb   = qkvb + (size_t)4096 * 3072;          // 2048*2048
  unsigned short* attnb = vtb  + (size_t)2048 * 2048;          // 4096*1024

  cvt_all<<<8192, 256, 0, stream>>>(x, w_qkv_w, w_o_w, xb, wqb, wob);
  gemm_bt<<<dim3(24, 32), 256, 0, stream>>>(xb, wqb, w_qkv_b, qkvb, vtb, 4096, 3072, 1024, 1024);
  attn_fwd<<<dim3(32, 32), 256, 0, stream>>>(qkvb, vtb, attnb);
  gemm_bt64<<<dim3(16, 32), 256, 0, stream>>>(attnb, wob, w_o_b, out, 4096, 1024, 1024);
}

// Round 14
// 179.619 us; speedup vs baseline: 1.0488x; 1.0039x over previous
//
#include <hip/hip_runtime.h>
#include <cstdint>
#include <cstddef>

// ---------------------------------------------------------------------------
// ChatGPTAttention: x[2,2048,1024] -> QKV proj -> causal MHA (16 heads, dk=64)
//                   -> O proj. bf16 MFMA pipeline, fp32 accumulate.
// Q pre-scaled by 1/8 in QKV-GEMM epilogue; V written transposed there (R14).
// FINAL CONFIG (R31 = restore of R11's 177.4us best):
//   gemm_bt: 128x128 BK=32, 3-buf rotating DMA + counted vmcnt (48KB LDS)
//   attn_fwd: v19 8-wave qxkv split, plain dbuf staging
//   gemm_bt64: 128x64 BK=64 dbuf
//   cvt_all: fused fp32->bf16 (BW-bound at its 48MB)
// FALSIFICATION MATRIX (complete):
//   attn: occupancy(R16/17) traffic(R20) balance(R21) chain(R22 sat/R26)
//         drain(R27) tile-count(R30) — all single-factor theories dead.
//   gemm: drain(R28), tile up(R24/25 deep-pipeline @K=1024), tile down(R29).
// Both kernels: mixed regime, all pipes 20-40%, no saturated roofline; the
// HK-class deep pipeline does not amortize at 16 K-tiles/block (R24/R25).
// Session: 186.5 -> 177.4us (R22 4-wave qxkv split was the win; R28 config
// hosts the best total). Terminal unless bench contradicts the restore.
// ---------------------------------------------------------------------------

typedef __attribute__((ext_vector_type(8))) short bf16x8;   // MFMA A/B frag
typedef __attribute__((ext_vector_type(4))) float f32x4;    // MFMA C/D frag
typedef __attribute__((ext_vector_type(4))) unsigned int u32x4;   // 16B copy
typedef __attribute__((ext_vector_type(4))) unsigned short u16x4; // 8B store
typedef __attribute__((ext_vector_type(8))) unsigned short u16x8; // 16B store

__device__ __forceinline__ unsigned short f2b(float f) {  // RNE f32->bf16
  unsigned int u = __float_as_uint(f);
  u = u + 0x7FFFu + ((u >> 16) & 1u);
  return (unsigned short)(u >> 16);
}
__device__ __forceinline__ unsigned short f2b_trunc(float f) {  // truncate
  return (unsigned short)(__float_as_uint(f) >> 16);
}

// async global->LDS DMA, 16B per lane; LDS dest = wave base + lane*16
__device__ __forceinline__ void gl_lds16(const unsigned short* g, unsigned short* s) {
  __builtin_amdgcn_global_load_lds((const __attribute__((address_space(1))) void*)g,
                                   (__attribute__((address_space(3))) void*)s, 16, 0, 0);
}

// ---------------- fp32 -> bf16, all three inputs in one launch -------------
__global__ __launch_bounds__(256) void cvt_all(const float* __restrict__ x,
                                               const float* __restrict__ wq,
                                               const float* __restrict__ wo,
                                               unsigned short* __restrict__ xb,
                                               unsigned short* __restrict__ wqb,
                                               unsigned short* __restrict__ wob) {
  const int bid = blockIdx.x;
  const float* in;
  unsigned short* out;
  int base;
  if (bid < 4096)      { in = x;  out = xb;  base = bid; }
  else if (bid < 7168) { in = wq; out = wqb; base = bid - 4096; }
  else                 { in = wo; out = wob; base = bid - 7168; }
  const int idx = (base * 256 + threadIdx.x) * 4;
  f32x4 v = *(const f32x4*)(in + idx);
  u16x4 r;
  r[0] = f2b(v[0]); r[1] = f2b(v[1]); r[2] = f2b(v[2]); r[3] = f2b(v[3]);
  *(u16x4*)(out + idx) = r;
}

// ---------------- GEMM: C[M,N] = (A[M,K] * W[N,K]^T + bias) * colscale -----
// 128x128 tile, BK=32, 3-deep rotating DMA buffers + counted vmcnt
// (48KB LDS, 3 blocks/CU). V-column blocks (n0>=2048) write transposed vt.
__global__ __launch_bounds__(256) void gemm_bt(const unsigned short* __restrict__ A,
                                               const unsigned short* __restrict__ W,
                                               const float* __restrict__ bias,
                                               unsigned short* __restrict__ Cb,
                                               unsigned short* __restrict__ vtb,
                                               int M, int N, int K, int qcols) {
  __shared__ unsigned short As[3][128 * 32];
  __shared__ unsigned short Bs[3][128 * 32];
  const int tid  = threadIdx.x;
  const int lane = tid & 63;
  const int w    = tid >> 6;
  const int wy   = w >> 1, wx = w & 1;
  const int l15  = lane & 15, quad = lane >> 4;
  const int xr2  = (l15 >> 1) & 3;
  const int m0 = blockIdx.y * 128, n0 = blockIdx.x * 128;

  const unsigned short* gA[2];
  const unsigned short* gB[2];
  int off[2];
#pragma unroll
  for (int p = 0; p < 2; ++p) {
    const int c = tid + p * 256;
    const int r = c >> 2;
    const int srcc = (c & 3) ^ ((r >> 1) & 3);
    gA[p] = A + (size_t)(m0 + r) * K + srcc * 8;
    gB[p] = W + (size_t)(n0 + r) * K + srcc * 8;
    off[p] = c * 8;
  }

  f32x4 acc[4][4];
#pragma unroll
  for (int i = 0; i < 4; ++i)
#pragma unroll
    for (int j = 0; j < 4; ++j) acc[i][j] = (f32x4){0.f, 0.f, 0.f, 0.f};

  // prologue: stage tile 0 -> buf0, tile 1 -> buf1 (8 loads outstanding)
#pragma unroll
  for (int p = 0; p < 2; ++p) {
    gl_lds16(gA[p], &As[0][off[p]]);
    gl_lds16(gB[p], &Bs[0][off[p]]);
  }
#pragma unroll
  for (int p = 0; p < 2; ++p) {
    gl_lds16(gA[p] + 32, &As[1][off[p]]);
    gl_lds16(gB[p] + 32, &Bs[1][off[p]]);
  }

  const int NIT = K >> 5;   // 32
  for (int it = 0; it < NIT; ++it) {
    // own ds_reads of the recycled buffer drained before the barrier
    asm volatile("s_waitcnt lgkmcnt(0)" ::: "memory");
    __builtin_amdgcn_s_barrier();
    // stage it+2 (or dummy re-stage of tile it into the dead buffer)
    {
      const int stg = (it + 2 < NIT) ? (it + 2) : it;
      const int bn  = (it + 2) % 3;
      const int kt  = stg << 5;
#pragma unroll
      for (int p = 0; p < 2; ++p) {
        gl_lds16(gA[p] + kt, &As[bn][off[p]]);
        gl_lds16(gB[p] + kt, &Bs[bn][off[p]]);
      }
    }
    asm volatile("s_waitcnt vmcnt(8)" ::: "memory");  // tile it resident
    __builtin_amdgcn_sched_barrier(0);
    const unsigned short* Ac = As[it % 3];
    const unsigned short* Bc = Bs[it % 3];
    bf16x8 af[4], bfr[4];
#pragma unroll
    for (int i = 0; i < 4; ++i)
      af[i] = *(const bf16x8*)&Ac[(wy * 64 + i * 16 + l15) * 32 + (quad ^ xr2) * 8];
#pragma unroll
    for (int j = 0; j < 4; ++j)
      bfr[j] = *(const bf16x8*)&Bc[(wx * 64 + j * 16 + l15) * 32 + (quad ^ xr2) * 8];
#pragma unroll
    for (int i = 0; i < 4; ++i)
#pragma unroll
      for (int j = 0; j < 4; ++j)
        acc[i][j] = __builtin_amdgcn_mfma_f32_16x16x32_bf16(af[i], bfr[j], acc[i][j], 0, 0, 0);
  }
  // drain dummies: in-flight DMA must not land in deallocated LDS
  asm volatile("s_waitcnt vmcnt(0)" ::: "memory");

  const bool vblock = (n0 >= 2048);  // block-uniform
#pragma unroll
  for (int i = 0; i < 4; ++i) {
    const int row = m0 + wy * 64 + i * 16 + quad * 4;
#pragma unroll
    for (int j = 0; j < 4; ++j) {
      const int col = n0 + wx * 64 + j * 16 + l15;
      const float bv = bias[col];
      if (!vblock) {
        const float sc = (col < qcols) ? 0.125f : 1.0f;
#pragma unroll
        for (int r = 0; r < 4; ++r)
          Cb[(size_t)(row + r) * N + col] = f2b((acc[i][j][r] + bv) * sc);
      } else {
        const int hd = col - 2048;
        const int bb = row >> 11, s = row & 2047;
        u16x4 ov;
#pragma unroll
        for (int r = 0; r < 4; ++r) ov[r] = f2b(acc[i][j][r] + bv);
        *(u16x4*)(vtb + ((size_t)(bb * 1024 + hd)) * 2048 + s) = ov;
      }
    }
  }
}

// ---------------- GEMM 128x64 tile, fp32 out (O-projection) ----------------
// R23 config. Grid (16,32)=512 blocks, LDS 48KB.
__global__ __launch_bounds__(256) void gemm_bt64(const unsigned short* __restrict__ A,
                                                 const unsigned short* __restrict__ W,
                                                 const float* __restrict__ bias,
                                                 float* __restrict__ Cf,
                                                 int M, int N, int K) {
  __shared__ unsigned short As[2][128 * 64];
  __shared__ unsigned short Bs[2][64 * 64];
  const int tid  = threadIdx.x;
  const int lane = tid & 63;
  const int w    = tid >> 6;
  const int wy   = w >> 1, wx = w & 1;
  const int l15  = lane & 15, quad = lane >> 4;
  const int xr   = l15 & 7;
  const int m0 = blockIdx.y * 128, n0 = blockIdx.x * 64;

  const unsigned short* gA[4];
  int offA[4];
#pragma unroll
  for (int p = 0; p < 4; ++p) {
    const int c = tid + p * 256;
    const int r = c >> 3;
    const int sc = ((c & 7) ^ (r & 7)) * 8;
    gA[p] = A + (size_t)(m0 + r) * K + sc;
    offA[p] = c * 8;
  }
  const unsigned short* gB[2];
  int offB[2];
#pragma unroll
  for (int p = 0; p < 2; ++p) {
    const int c = tid + p * 256;
    const int r = c >> 3;
    const int sc = ((c & 7) ^ (r & 7)) * 8;
    gB[p] = W + (size_t)(n0 + r) * K + sc;
    offB[p] = c * 8;
  }

  f32x4 acc[4][2];
#pragma unroll
  for (int i = 0; i < 4; ++i)
#pragma unroll
    for (int j = 0; j < 2; ++j) acc[i][j] = (f32x4){0.f, 0.f, 0.f, 0.f};

#pragma unroll
  for (int p = 0; p < 4; ++p) gl_lds16(gA[p], &As[0][offA[p]]);
#pragma unroll
  for (int p = 0; p < 2; ++p) gl_lds16(gB[p], &Bs[0][offB[p]]);

  const int NIT = K >> 6;
  for (int it = 0; it < NIT; ++it) {
    __syncthreads();
    const int cur = it & 1;
    if (it + 1 < NIT) {
      const int kt = (it + 1) << 6;
#pragma unroll
      for (int p = 0; p < 4; ++p) gl_lds16(gA[p] + kt, &As[cur ^ 1][offA[p]]);
#pragma unroll
      for (int p = 0; p < 2; ++p) gl_lds16(gB[p] + kt, &Bs[cur ^ 1][offB[p]]);
    }
    const unsigned short* Ac = As[cur];
    const unsigned short* Bc = Bs[cur];
#pragma unroll
    for (int kc = 0; kc < 2; ++kc) {
      bf16x8 af[4], bfr[2];
#pragma unroll
      for (int i = 0; i < 4; ++i)
        af[i] = *(const bf16x8*)&Ac[(wy * 64 + i * 16 + l15) * 64 + ((kc * 4 + quad) ^ xr) * 8];
#pragma unroll
      for (int j = 0; j < 2; ++j)
        bfr[j] = *(const bf16x8*)&Bc[(wx * 32 + j * 16 + l15) * 64 + ((kc * 4 + quad) ^ xr) * 8];
#pragma unroll
      for (int i = 0; i < 4; ++i)
#pragma unroll
        for (int j = 0; j < 2; ++j)
          acc[i][j] = __builtin_amdgcn_mfma_f32_16x16x32_bf16(af[i], bfr[j], acc[i][j], 0, 0, 0);
    }
  }

#pragma unroll
  for (int i = 0; i < 4; ++i) {
    const int row = m0 + wy * 64 + i * 16 + quad * 4;
#pragma unroll
    for (int j = 0; j < 2; ++j) {
      const int col = n0 + wx * 32 + j * 16 + l15;
      const float bv = bias[col];
#pragma unroll
      for (int r = 0; r < 4; ++r)
        Cf[(size_t)(row + r) * N + col] = acc[i][j][r] + bv;
    }
  }
}

// ---------------- flash attention v19: 8-wave q x kv split (R26) -----------
// Block = 8 waves (wq 0..3 x wk 0..1), 512 thr; grid (bh 32, y 32). Wave:
// 16 q x 32 kv. Plain dbuf __syncthreads staging. Combine via dead Ks/Vs.
__global__ __launch_bounds__(512, 6) void attn_fwd(const unsigned short* __restrict__ qkv,
                                                   const unsigned short* __restrict__ vt,
                                                   unsigned short* __restrict__ o) {
  __shared__ unsigned short Ks[2][64 * 64];
  __shared__ unsigned short Vs[2][64 * 64];
  __shared__ unsigned short pbuf[8][16 * 40];  // [wave][16 q x (32+8) kv]
  const int tid  = threadIdx.x;
  const int lane = tid & 63;
  const int w    = tid >> 6;          // 8 waves
  const int wq   = w & 3;             // q-quarter (16 q)
  const int wk   = w >> 2;            // kv-half (32 kv)
  const int l15  = lane & 15, quad = lane >> 4;
  const int xr   = l15 & 7;
  const int bh = blockIdx.x, b = bh >> 4, h = bh & 15;
  const int y  = (int)blockIdx.y;
  const int qt = (y < 16) ? y : 47 - y;  // per-CU balanced (R21)
  const int q0 = qt * 64;
  const int T = qt + 1;
  const int qs = q0 + wq * 16;        // this wave's q base (16 rows)

  // DMA staging: 512 chunks per 64x64 tile / 512 threads = 1/thread/array.
  const int r  = tid >> 3;
  const int sc = ((tid & 7) ^ (r & 7)) * 8;
  const unsigned short* gKd = qkv + (size_t)(b * 2048 + r) * 3072 + 1024 + h * 64 + sc;
  const unsigned short* gVd = vt + (size_t)(bh * 64 + r) * 2048 + sc;
  const int doff = tid * 8;

  const unsigned short* qr = qkv + (size_t)(b * 2048 + qs + l15) * 3072 + h * 64;
  const bf16x8 bq[2] = { *(const bf16x8*)(qr + quad * 8),
                         *(const bf16x8*)(qr + 32 + quad * 8) };

  bf16x8 vones;
#pragma unroll
  for (int k = 0; k < 8; ++k) vones[k] = (short)0x3F80;  // bf16 1.0

  f32x4 acc[4];      // [d-tile], PARTIAL over this wave's kv-half
#pragma unroll
  for (int j = 0; j < 4; ++j) acc[j] = (f32x4){0.f, 0.f, 0.f, 0.f};
  f32x4 accL = (f32x4){0.f, 0.f, 0.f, 0.f};

  unsigned short* P = pbuf[w];

  // prologue: DMA tile 0 -> buf 0
  gl_lds16(gKd, &Ks[0][doff]);
  gl_lds16(gVd, &Vs[0][doff]);

  for (int t = 0; t < T; ++t) {
    __syncthreads();  // drains DMA for buf(t&1)
    const int cur = t & 1;
    if (t + 1 < T) {
      const size_t ko = (size_t)(t + 1) * 64 * 3072;
      const int vo = (t + 1) * 64;
      gl_lds16(gKd + ko, &Ks[cur ^ 1][doff]);
      gl_lds16(gVd + vo, &Vs[cur ^ 1][doff]);
    }
    const unsigned short* Kc = Ks[cur];
    const unsigned short* Vc = Vs[cur];
    const int kv0 = t * 64 + wk * 32;   // this wave's kv base

    // ---- S^T[kv][q] = K Q^T, this wave's 32 kv x 16 q ----
    f32x4 st[2];
#pragma unroll
    for (int n = 0; n < 2; ++n) {
      const int row = wk * 32 + n * 16 + l15;
      const bf16x8 kA0 = *(const bf16x8*)&Kc[row * 64 + ((quad) ^ xr) * 8];
      const bf16x8 kA1 = *(const bf16x8*)&Kc[row * 64 + ((4 + quad) ^ xr) * 8];
      f32x4 z = (f32x4){0.f, 0.f, 0.f, 0.f};
      z = __builtin_amdgcn_mfma_f32_16x16x32_bf16(kA0, bq[0], z, 0, 0, 0);
      z = __builtin_amdgcn_mfma_f32_16x16x32_bf16(kA1, bq[1], z, 0, 0, 0);
      st[n] = z;
    }
    // ---- V^T A-frags for this kv-half ----
    bf16x8 av[4];
#pragma unroll
    for (int j = 0; j < 4; ++j) {
      const int row = j * 16 + l15;
      av[j] = *(const bf16x8*)&Vc[row * 64 + ((wk * 4 + quad) ^ xr) * 8];
    }
    // ---- mask/exp + P write ----
    if (kv0 + 31 > qs) {
      const int qrow = qs + l15;
#pragma unroll
      for (int n = 0; n < 2; ++n)
#pragma unroll
        for (int rr = 0; rr < 4; ++rr)
          if (kv0 + n * 16 + quad * 4 + rr > qrow) st[n][rr] = -1e30f;
    }
#pragma unroll
    for (int n = 0; n < 2; ++n) {
#pragma unroll
      for (int rr = 0; rr < 4; ++rr) st[n][rr] = __expf(st[n][rr]);
      u16x4 pw;
      pw[0] = f2b_trunc(st[n][0]); pw[1] = f2b_trunc(st[n][1]);
      pw[2] = f2b_trunc(st[n][2]); pw[3] = f2b_trunc(st[n][3]);
      *(u16x4*)&P[l15 * 40 + n * 16 + quad * 4] = pw;
    }
    // ---- Pr + PV (K=32 contraction) ----
    {
      const bf16x8 bp = *(const bf16x8*)&P[l15 * 40 + quad * 8];
      accL = __builtin_amdgcn_mfma_f32_16x16x32_bf16(vones, bp, accL, 0, 0, 0);
#pragma unroll
      for (int j = 0; j < 4; ++j)
        acc[j] = __builtin_amdgcn_mfma_f32_16x16x32_bf16(av[j], bp, acc[j], 0, 0, 0);
    }
  }

  // ---- cross-wave kv-half combine (once per block; K/V buffers dead) ----
  __syncthreads();
  float* cmbA = (float*)&Ks[0][0];   // 16 frags x 1KB = 16KB = Ks
  float* cmbL = (float*)&Vs[0][0];   // 4 x 64 floats = 1KB
  if (wk == 1) {
    cmbL[wq * 64 + lane] = accL[0];
#pragma unroll
    for (int j = 0; j < 4; ++j)
      *(f32x4*)&cmbA[((wq * 4 + j) << 8) + lane * 4] = acc[j];
  }
  __syncthreads();
  if (wk == 0) {
    const float lsum = accL[0] + cmbL[wq * 64 + lane];
    const float inv = 1.0f / lsum;
    const int qrow = qs + l15;
    unsigned short* orow = o + (size_t)(b * 2048 + qrow) * 1024 + h * 64;
#pragma unroll
    for (int j = 0; j < 4; ++j) {
      const f32x4 oth = *(const f32x4*)&cmbA[((wq * 4 + j) << 8) + lane * 4];
      u16x4 ov;
      ov[0] = f2b((acc[j][0] + oth[0]) * inv);
      ov[1] = f2b((acc[j][1] + oth[1]) * inv);
      ov[2] = f2b((acc[j][2] + oth[2]) * inv);
      ov[3] = f2b((acc[j][3] + oth[3]) * inv);
      *(u16x4*)(orow + j * 16 + quad * 4) = ov;
    }
  }
}

// ---------------------------------------------------------------------------
extern "C" void kernel_launch(void* const* d_in, const int* in_sizes, int n_in,
                              void* d_out, int out_size, void* d_ws, size_t ws_size,
                              hipStream_t stream) {
  const float* x       = (const float*)d_in[0];
  // d_in[1] = mask: causal tril by construction; implemented analytically.
  const float* w_qkv_w = (const float*)d_in[2];
  const float* w_qkv_b = (const float*)d_in[3];
  const float* w_o_w   = (const float*)d_in[4];
  const float* w_o_b   = (const float*)d_in[5];
  float* out = (float*)d_out;

  unsigned short* ws    = (unsigned short*)d_ws;
  unsigned short* xb    = ws;                                  // 4096*1024
  unsigned short* wqb   = xb   + (size_t)4096 * 1024;          // 3072*1024
  unsigned short* wob   = wqb  + (size_t)3072 * 1024;          // 1024*1024
  unsigned short* qkvb  = wob  + (size_t)1024 * 1024;          // 4096*3072
  unsigned short* vtb   = qkvb + (size_t)4096 * 3072;          // 2048*2048
  unsigned short* attnb = vtb  + (size_t)2048 * 2048;          // 4096*1024

  cvt_all<<<8192, 256, 0, stream>>>(x, w_qkv_w, w_o_w, xb, wqb, wob);
  gemm_bt<<<dim3(24, 32), 256, 0, stream>>>(xb, wqb, w_qkv_b, qkvb, vtb, 4096, 3072, 1024, 1024);
  attn_fwd<<<dim3(32, 32), 512, 0, stream>>>(qkvb, vtb, attnb);
  gemm_bt64<<<dim3(16, 32), 256, 0, stream>>>(attnb, wob, w_o_b, out, 4096, 1024, 1024);
}